// Round 1
// baseline (158.286 us; speedup 1.0000x reference)
//
#include <hip/hip_runtime.h>
#include <hip/hip_bf16.h>

#define T_DIM 4096
#define E_DIM 2048
#define D_DIM 256
#define SPLIT 8

typedef __attribute__((ext_vector_type(4))) float f32x4;
typedef __attribute__((ext_vector_type(8))) short s16x8;

__device__ __forceinline__ unsigned short f2bf(float f) {
  unsigned int u = __float_as_uint(f);
  unsigned int r = (u + 0x7FFFu + ((u >> 16) & 1u)) >> 16;  // RNE
  return (unsigned short)r;
}

__device__ __forceinline__ f32x4 mfma16(s16x8 a, s16x8 b, f32x4 c) {
  return __builtin_amdgcn_mfma_f32_16x16x32_bf16(a, b, c, 0, 0, 0);
}

__device__ __forceinline__ void gload_lds16(const void* g, void* l) {
  __builtin_amdgcn_global_load_lds((const __attribute__((address_space(1))) void*)g,
                                   (__attribute__((address_space(3))) void*)l, 16, 0, 0);
}

// ---------------- fp32 -> bf16 convert (vectorized, 8 elems/thread) ----------
__global__ __launch_bounds__(256) void cvt_kernel(const float* __restrict__ src,
                                                  unsigned short* __restrict__ dst, int n) {
  int i = blockIdx.x * blockDim.x + threadIdx.x;
  if (i * 8 + 8 <= n) {
    float4 a = ((const float4*)src)[i * 2];
    float4 b = ((const float4*)src)[i * 2 + 1];
    uint4 o;
    o.x = (unsigned int)f2bf(a.x) | ((unsigned int)f2bf(a.y) << 16);
    o.y = (unsigned int)f2bf(a.z) | ((unsigned int)f2bf(a.w) << 16);
    o.z = (unsigned int)f2bf(b.x) | ((unsigned int)f2bf(b.y) << 16);
    o.w = (unsigned int)f2bf(b.z) | ((unsigned int)f2bf(b.w) << 16);
    ((uint4*)dst)[i] = o;
  }
}

// ---------------- fused QKV projection GEMM -----------------------------------
// C[4096, 768] = xb[4096,2048] @ wb[768,2048]^T ; cols 0-255 -> Q, 256-511 -> K,
// 512-767 -> V stored transposed (Vt[256][4096]).
__global__ __launch_bounds__(256, 2) void qkv_gemm(
    const unsigned short* __restrict__ xb, const unsigned short* __restrict__ wb,
    unsigned short* __restrict__ Qg, unsigned short* __restrict__ Kg,
    unsigned short* __restrict__ Vt) {
  __shared__ __align__(16) unsigned short Al[128 * 32];
  __shared__ __align__(16) unsigned short Bl[128 * 32];
  int tid = threadIdx.x;
  int wid = tid >> 6;
  int lane = tid & 63;
  int lr = lane & 15;
  int lk = lane >> 4;
  int bm0 = (int)(blockIdx.x & 31) * 128;
  int bn0 = (int)(blockIdx.x >> 5) * 128;
  int wm = (wid >> 1) * 64;
  int wn = (wid & 1) * 64;

  f32x4 acc[4][4];
#pragma unroll
  for (int m = 0; m < 4; ++m)
#pragma unroll
    for (int n = 0; n < 4; ++n) acc[m][n] = (f32x4){0.f, 0.f, 0.f, 0.f};

  for (int kt = 0; kt < E_DIM / 32; ++kt) {
    int k0 = kt * 32;
#pragma unroll
    for (int i = 0; i < 2; ++i) {
      int c = i * 256 + wid * 64 + lane;       // chunk id 0..511, 16B each
      int row = c >> 2;
      int kc8 = (c & 3) << 3;
      gload_lds16(&xb[(size_t)(bm0 + row) * E_DIM + k0 + kc8],
                  &Al[(size_t)(i * 256 + wid * 64) * 8]);
      gload_lds16(&wb[(size_t)(bn0 + row) * E_DIM + k0 + kc8],
                  &Bl[(size_t)(i * 256 + wid * 64) * 8]);
    }
    __syncthreads();
    s16x8 af[4], bfr[4];
#pragma unroll
    for (int m = 0; m < 4; ++m)
      af[m] = *(const s16x8*)&Al[(wm + m * 16 + lr) * 32 + lk * 8];
#pragma unroll
    for (int n = 0; n < 4; ++n)
      bfr[n] = *(const s16x8*)&Bl[(wn + n * 16 + lr) * 32 + lk * 8];
#pragma unroll
    for (int m = 0; m < 4; ++m)
#pragma unroll
      for (int n = 0; n < 4; ++n) acc[m][n] = mfma16(af[m], bfr[n], acc[m][n]);
    __syncthreads();
  }

  // epilogue: C layout col=lane&15, row=(lane>>4)*4+reg
#pragma unroll
  for (int m = 0; m < 4; ++m) {
    int grow = bm0 + wm + m * 16 + lk * 4;
#pragma unroll
    for (int n = 0; n < 4; ++n) {
      int gcol = bn0 + wn + n * 16 + lr;
      unsigned short h[4];
#pragma unroll
      for (int r = 0; r < 4; ++r) h[r] = f2bf(acc[m][n][r]);
      if (gcol < 256) {
#pragma unroll
        for (int r = 0; r < 4; ++r) Qg[(size_t)(grow + r) * D_DIM + gcol] = h[r];
      } else if (gcol < 512) {
#pragma unroll
        for (int r = 0; r < 4; ++r) Kg[(size_t)(grow + r) * D_DIM + gcol - 256] = h[r];
      } else {
        uint2 w;
        w.x = (unsigned int)h[0] | ((unsigned int)h[1] << 16);
        w.y = (unsigned int)h[2] | ((unsigned int)h[3] << 16);
        *(uint2*)&Vt[(size_t)(gcol - 512) * T_DIM + grow] = w;
      }
    }
  }
}

// ---------------- flash attention (causal), split-KV partials -----------------
// grid = 64 tiles(of 64 q rows) x SPLIT ; block = 4 waves, wave w owns 16 q rows.
// Swapped QK^T: S^T = mfma(K, Q): lane holds S[q = lane&15][key = jb*16+(lane>>4)*4+r].
__global__ __launch_bounds__(256, 2) void attn_kernel(
    const unsigned short* __restrict__ Qg, const unsigned short* __restrict__ Kg,
    const unsigned short* __restrict__ Vt, float* __restrict__ Opart,
    float* __restrict__ mpart, float* __restrict__ lpart) {
  int b = blockIdx.x;
  int t = b >> 3;
  int s = b & (SPLIT - 1);
  int tid = threadIdx.x;
  int wid = tid >> 6;
  int lane = tid & 63;
  int lr = lane & 15;
  int lk = lane >> 4;
  int q0 = t * 64 + wid * 16;

  __shared__ __align__(16) unsigned short Pl[4][16 * 80];  // per-wave P^T buffer
  unsigned short* pl = &Pl[wid][0];

  s16x8 qf[8];
#pragma unroll
  for (int c = 0; c < 8; ++c)
    qf[c] = *(const s16x8*)&Qg[(size_t)(q0 + lr) * D_DIM + c * 32 + lk * 8];

  float m_run = -1e30f, l_run = 0.0f;
  f32x4 Oa[16];
#pragma unroll
  for (int d = 0; d < 16; ++d) Oa[d] = (f32x4){0.f, 0.f, 0.f, 0.f};

  const float scale = 0.0625f;  // 1/sqrt(256)

  for (int j = s; j <= t; j += SPLIT) {
    int kv = j * 64;
    f32x4 sa[4];
#pragma unroll
    for (int jb = 0; jb < 4; ++jb) sa[jb] = (f32x4){0.f, 0.f, 0.f, 0.f};
#pragma unroll
    for (int jb = 0; jb < 4; ++jb) {
#pragma unroll
      for (int c = 0; c < 8; ++c) {
        s16x8 kf = *(const s16x8*)&Kg[(size_t)(kv + jb * 16 + lr) * D_DIM + c * 32 + lk * 8];
        sa[jb] = mfma16(kf, qf[c], sa[jb]);
      }
    }
    // scale + causal mask (only diagonal block j==t needs it)
    float tmax = -1e30f;
    bool diag = (j == t);
#pragma unroll
    for (int jb = 0; jb < 4; ++jb) {
#pragma unroll
      for (int r = 0; r < 4; ++r) {
        float v = sa[jb][r] * scale;
        if (diag && (jb * 16 + lk * 4 + r) > (wid * 16 + lr)) v = -1e30f;
        sa[jb][r] = v;
        tmax = fmaxf(tmax, v);
      }
    }
    tmax = fmaxf(tmax, __shfl_xor(tmax, 16));
    tmax = fmaxf(tmax, __shfl_xor(tmax, 32));
    float m_new = fmaxf(m_run, tmax);
    float alpha = __expf(m_run - m_new);
    float psum = 0.f;
#pragma unroll
    for (int jb = 0; jb < 4; ++jb) {
      float p0 = __expf(sa[jb][0] - m_new);
      float p1 = __expf(sa[jb][1] - m_new);
      float p2 = __expf(sa[jb][2] - m_new);
      float p3 = __expf(sa[jb][3] - m_new);
      psum += (p0 + p1) + (p2 + p3);
      uint2 w;
      w.x = (unsigned int)f2bf(p0) | ((unsigned int)f2bf(p1) << 16);
      w.y = (unsigned int)f2bf(p2) | ((unsigned int)f2bf(p3) << 16);
      // P^T transpose through per-wave LDS: P_lds[q=lr][key]
      *(uint2*)&pl[lr * 80 + jb * 16 + lk * 4] = w;
    }
    psum += __shfl_xor(psum, 16);
    psum += __shfl_xor(psum, 32);
    l_run = l_run * alpha + psum;
    m_run = m_new;
    // rescale O rows (row q = lk*4+r needs alpha computed by lane lk*4+r)
    float al[4];
#pragma unroll
    for (int r = 0; r < 4; ++r) al[r] = __shfl(alpha, lk * 4 + r);
#pragma unroll
    for (int d = 0; d < 16; ++d) {
#pragma unroll
      for (int r = 0; r < 4; ++r) Oa[d][r] *= al[r];
    }
    // PV: A = P (from LDS), B = V fragments from Vt (contiguous 16B)
    s16x8 pf0 = *(const s16x8*)&pl[lr * 80 + lk * 8];
    s16x8 pf1 = *(const s16x8*)&pl[lr * 80 + 32 + lk * 8];
#pragma unroll
    for (int d = 0; d < 16; ++d) {
      s16x8 vf0 = *(const s16x8*)&Vt[(size_t)(d * 16 + lr) * T_DIM + kv + lk * 8];
      Oa[d] = mfma16(pf0, vf0, Oa[d]);
    }
#pragma unroll
    for (int d = 0; d < 16; ++d) {
      s16x8 vf1 = *(const s16x8*)&Vt[(size_t)(d * 16 + lr) * T_DIM + kv + 32 + lk * 8];
      Oa[d] = mfma16(pf1, vf1, Oa[d]);
    }
  }

  // store partials (unnormalized O, running m and l)
  float* Op = Opart + ((size_t)s * T_DIM + q0) * D_DIM;
#pragma unroll
  for (int d = 0; d < 16; ++d) {
#pragma unroll
    for (int r = 0; r < 4; ++r)
      Op[(size_t)(lk * 4 + r) * D_DIM + d * 16 + lr] = Oa[d][r];
  }
  if (lane < 16) {
    mpart[(size_t)s * T_DIM + q0 + lr] = m_run;
    lpart[(size_t)s * T_DIM + q0 + lr] = l_run;
  }
}

// ---------------- merge split-KV partials -> final output ---------------------
__global__ __launch_bounds__(256) void merge_kernel(const float* __restrict__ Opart,
                                                    const float* __restrict__ mpart,
                                                    const float* __restrict__ lpart,
                                                    float* __restrict__ out) {
  int q = blockIdx.x;
  int d = threadIdx.x;
  float ms[SPLIT], ls[SPLIT];
  float M = -1e30f;
#pragma unroll
  for (int s = 0; s < SPLIT; ++s) {
    ms[s] = mpart[(size_t)s * T_DIM + q];
    ls[s] = lpart[(size_t)s * T_DIM + q];
    M = fmaxf(M, ms[s]);
  }
  float denom = 0.f, acc = 0.f;
#pragma unroll
  for (int s = 0; s < SPLIT; ++s) {
    float w = __expf(ms[s] - M);
    denom += w * ls[s];
    acc += w * Opart[((size_t)s * T_DIM + q) * D_DIM + d];
  }
  out[(size_t)q * D_DIM + d] = acc / denom;
}

// ---------------- host launch --------------------------------------------------
extern "C" void kernel_launch(void* const* d_in, const int* in_sizes, int n_in,
                              void* d_out, int out_size, void* d_ws, size_t ws_size,
                              hipStream_t stream) {
  const float* x  = (const float*)d_in[0];
  const float* Wq = (const float*)d_in[1];
  const float* Wk = (const float*)d_in[2];
  const float* Wv = (const float*)d_in[3];

  char* ws = (char*)d_ws;
  // workspace layout (bytes):
  //   xb   [4096][2048] bf16 : 16,777,216
  //   wb   [768][2048]  bf16 :  3,145,728
  //   Qg   [4096][256]  bf16 :  2,097,152
  //   Kg   [4096][256]  bf16 :  2,097,152
  //   Vt   [256][4096]  bf16 :  2,097,152
  //   Opart[8][4096][256] f32: 33,554,432
  //   mpart/lpart [8][4096] f32: 131,072 each      (total ~57.4 MiB)
  unsigned short* xb = (unsigned short*)(ws);
  unsigned short* wb = (unsigned short*)(ws + 16777216);
  unsigned short* Qg = (unsigned short*)(ws + 19922944);
  unsigned short* Kg = (unsigned short*)(ws + 22020096);
  unsigned short* Vt = (unsigned short*)(ws + 24117248);
  float* Opart = (float*)(ws + 26214400);
  float* mpart = (float*)(ws + 59768832);
  float* lpart = (float*)(ws + 59899904);

  cvt_kernel<<<4096, 256, 0, stream>>>(x, xb, T_DIM * E_DIM);
  cvt_kernel<<<256, 256, 0, stream>>>(Wq, wb, D_DIM * E_DIM);
  cvt_kernel<<<256, 256, 0, stream>>>(Wk, wb + (size_t)D_DIM * E_DIM, D_DIM * E_DIM);
  cvt_kernel<<<256, 256, 0, stream>>>(Wv, wb + (size_t)2 * D_DIM * E_DIM, D_DIM * E_DIM);

  qkv_gemm<<<32 * 6, 256, 0, stream>>>(xb, wb, Qg, Kg, Vt);

  attn_kernel<<<64 * SPLIT, 256, 0, stream>>>(Qg, Kg, Vt, Opart, mpart, lpart);

  merge_kernel<<<T_DIM, 256, 0, stream>>>(Opart, mpart, lpart, (float*)d_out);
}

// Round 2
// 121.401 us; speedup vs baseline: 1.3038x; 1.3038x over previous
//
#include <hip/hip_runtime.h>
#include <hip/hip_bf16.h>

#define T_DIM 4096
#define E_DIM 2048
#define D_DIM 256
#define SPLIT 8

typedef __attribute__((ext_vector_type(4))) float f32x4;
typedef __attribute__((ext_vector_type(8))) short s16x8;

__device__ __forceinline__ unsigned short f2bf(float f) {
  unsigned int u = __float_as_uint(f);
  unsigned int r = (u + 0x7FFFu + ((u >> 16) & 1u)) >> 16;  // RNE
  return (unsigned short)r;
}

__device__ __forceinline__ f32x4 mfma16(s16x8 a, s16x8 b, f32x4 c) {
  return __builtin_amdgcn_mfma_f32_16x16x32_bf16(a, b, c, 0, 0, 0);
}

__device__ __forceinline__ void gload_lds16(const void* g, void* l) {
  __builtin_amdgcn_global_load_lds((const __attribute__((address_space(1))) void*)g,
                                   (__attribute__((address_space(3))) void*)l, 16, 0, 0);
}

// ---------------- fp32 -> bf16 convert (vectorized, 8 elems/thread) ----------
__global__ __launch_bounds__(256) void cvt_kernel(const float* __restrict__ src,
                                                  unsigned short* __restrict__ dst, int n) {
  int i = blockIdx.x * blockDim.x + threadIdx.x;
  if (i * 8 + 8 <= n) {
    float4 a = ((const float4*)src)[i * 2];
    float4 b = ((const float4*)src)[i * 2 + 1];
    uint4 o;
    o.x = (unsigned int)f2bf(a.x) | ((unsigned int)f2bf(a.y) << 16);
    o.y = (unsigned int)f2bf(a.z) | ((unsigned int)f2bf(a.w) << 16);
    o.z = (unsigned int)f2bf(b.x) | ((unsigned int)f2bf(b.y) << 16);
    o.w = (unsigned int)f2bf(b.z) | ((unsigned int)f2bf(b.w) << 16);
    ((uint4*)dst)[i] = o;
  }
}

// ---------------- fused QKV projection GEMM -----------------------------------
// C[4096, 768] = xb[4096,2048] @ wb[768,2048]^T. BM=128, BN=64, BK=32.
// grid = 32 M-tiles * 12 N-tiles = 384 blocks; 4 waves (2x2), wave tile 64x32.
// cols 0-255 -> Q, 256-511 -> K, 512-767 -> V stored transposed (Vt[256][4096]).
__global__ __launch_bounds__(256, 3) void qkv_gemm(
    const unsigned short* __restrict__ xb, const unsigned short* __restrict__ wb,
    unsigned short* __restrict__ Qg, unsigned short* __restrict__ Kg,
    unsigned short* __restrict__ Vt) {
  __shared__ __align__(16) unsigned short Al[128 * 32];
  __shared__ __align__(16) unsigned short Bl[64 * 32];
  int tid = threadIdx.x;
  int wid = tid >> 6;
  int lane = tid & 63;
  int lr = lane & 15;
  int lk = lane >> 4;
  int bm0 = (int)(blockIdx.x & 31) * 128;
  int bn0 = (int)(blockIdx.x >> 5) * 64;
  int wm = (wid >> 1) * 64;
  int wn = (wid & 1) * 32;

  f32x4 acc[4][2];
#pragma unroll
  for (int m = 0; m < 4; ++m)
#pragma unroll
    for (int n = 0; n < 2; ++n) acc[m][n] = (f32x4){0.f, 0.f, 0.f, 0.f};

  for (int kt = 0; kt < E_DIM / 32; ++kt) {
    int k0 = kt * 32;
    // stage A: 512 chunks of 16B, 2 wave-calls per wave
#pragma unroll
    for (int i = 0; i < 2; ++i) {
      int ci = (wid * 2 + i) * 64 + lane;      // 0..511
      int row = ci >> 2;
      int c8 = (ci & 3) << 3;
      gload_lds16(&xb[(size_t)(bm0 + row) * E_DIM + k0 + c8],
                  &Al[(size_t)((wid * 2 + i) * 64) * 8]);
    }
    // stage B: 256 chunks, 1 wave-call per wave
    {
      int cb = wid * 64 + lane;                // 0..255
      gload_lds16(&wb[(size_t)(bn0 + (cb >> 2)) * E_DIM + k0 + ((cb & 3) << 3)],
                  &Bl[(size_t)(wid * 64) * 8]);
    }
    __syncthreads();
    s16x8 af[4], bfr[2];
#pragma unroll
    for (int m = 0; m < 4; ++m)
      af[m] = *(const s16x8*)&Al[(wm + m * 16 + lr) * 32 + lk * 8];
#pragma unroll
    for (int n = 0; n < 2; ++n)
      bfr[n] = *(const s16x8*)&Bl[(wn + n * 16 + lr) * 32 + lk * 8];
#pragma unroll
    for (int m = 0; m < 4; ++m)
#pragma unroll
      for (int n = 0; n < 2; ++n) acc[m][n] = mfma16(af[m], bfr[n], acc[m][n]);
    __syncthreads();
  }

  // epilogue: C layout col=lane&15, row=(lane>>4)*4+reg
#pragma unroll
  for (int m = 0; m < 4; ++m) {
    int grow = bm0 + wm + m * 16 + lk * 4;
#pragma unroll
    for (int n = 0; n < 2; ++n) {
      int gcol = bn0 + wn + n * 16 + lr;
      unsigned short h[4];
#pragma unroll
      for (int r = 0; r < 4; ++r) h[r] = f2bf(acc[m][n][r]);
      if (gcol < 256) {
#pragma unroll
        for (int r = 0; r < 4; ++r) Qg[(size_t)(grow + r) * D_DIM + gcol] = h[r];
      } else if (gcol < 512) {
#pragma unroll
        for (int r = 0; r < 4; ++r) Kg[(size_t)(grow + r) * D_DIM + gcol - 256] = h[r];
      } else {
        uint2 w;
        w.x = (unsigned int)h[0] | ((unsigned int)h[1] << 16);
        w.y = (unsigned int)h[2] | ((unsigned int)h[3] << 16);
        *(uint2*)&Vt[(size_t)(gcol - 512) * T_DIM + grow] = w;
      }
    }
  }
}

// ---------------- flash attention (causal), split-KV partials -----------------
// grid = 64 q-tiles(64 rows) x SPLIT; block = 4 waves, wave w owns 16 q rows.
// K-tile staged in LDS (double-buffered, async global_load_lds, XOR-swizzled).
// Swapped QK^T: S^T = mfma(K, Q): lane holds S[key = jb*16+lk*4+r][q = lr].
__global__ __launch_bounds__(256, 2) void attn_kernel(
    const unsigned short* __restrict__ Qg, const unsigned short* __restrict__ Kg,
    const unsigned short* __restrict__ Vt, float* __restrict__ Opart,
    float* __restrict__ mpart, float* __restrict__ lpart) {
  __shared__ __align__(16) unsigned short Kl[2][64 * 256];  // swizzled K tiles
  __shared__ __align__(16) unsigned short Pl[4][16 * 80];   // per-wave P^T buffer

  int b = blockIdx.x;
  int tt = b >> 3;
  // heavy/light pairing for causal load balance: (63,0),(62,1),...
  int t = (tt & 1) ? (tt >> 1) : (63 - (tt >> 1));
  int s = b & (SPLIT - 1);
  int tid = threadIdx.x;
  int wid = tid >> 6;
  int lane = tid & 63;
  int lr = lane & 15;
  int lk = lane >> 4;
  int q0 = t * 64 + wid * 16;
  unsigned short* pl = &Pl[wid][0];

  s16x8 qf[8];
#pragma unroll
  for (int c = 0; c < 8; ++c)
    qf[c] = *(const s16x8*)&Qg[(size_t)(q0 + lr) * D_DIM + c * 32 + lk * 8];

  float m_run = -1e30f, l_run = 0.0f;
  f32x4 Oa[16];
#pragma unroll
  for (int d = 0; d < 16; ++d) Oa[d] = (f32x4){0.f, 0.f, 0.f, 0.f};

  const float scale = 0.0625f;  // 1/sqrt(256)
  int nt = (t >= s) ? ((t - s) >> 3) + 1 : 0;

  if (nt > 0) {
    // initial stage into buf 0: 2048 chunks, 8 wave-calls per wave.
    // LDS slot (row, cc) holds global chunk (row, cc ^ (row&7))  [involution]
#pragma unroll
    for (int i = 0; i < 8; ++i) {
      int slot = wid * 512 + i * 64 + lane;
      int row = slot >> 5;
      int cc = slot & 31;
      gload_lds16(&Kg[(size_t)(s * 64 + row) * D_DIM + ((cc ^ (row & 7)) << 3)],
                  &Kl[0][(size_t)(wid * 512 + i * 64) * 8]);
    }

    for (int n = 0; n < nt; ++n) {
      int j = s + n * SPLIT;
      int kv = j * 64;
      int cur = n & 1;
      __syncthreads();  // drains this wave's stage loads (vmcnt 0) + syncs block
      if (n + 1 < nt) {
        int kvn = kv + SPLIT * 64;
#pragma unroll
        for (int i = 0; i < 8; ++i) {
          int slot = wid * 512 + i * 64 + lane;
          int row = slot >> 5;
          int cc = slot & 31;
          gload_lds16(&Kg[(size_t)(kvn + row) * D_DIM + ((cc ^ (row & 7)) << 3)],
                      &Kl[cur ^ 1][(size_t)(wid * 512 + i * 64) * 8]);
        }
      }
      const unsigned short* kl = &Kl[cur][0];

      // ---- QK^T from LDS (swizzled read) ----
      f32x4 sa[4];
#pragma unroll
      for (int jb = 0; jb < 4; ++jb) sa[jb] = (f32x4){0.f, 0.f, 0.f, 0.f};
#pragma unroll
      for (int jb = 0; jb < 4; ++jb) {
        int row = jb * 16 + lr;
#pragma unroll
        for (int c = 0; c < 8; ++c) {
          s16x8 kf = *(const s16x8*)&kl[row * 256 + (((c * 4 + lk) ^ (lr & 7)) << 3)];
          sa[jb] = mfma16(kf, qf[c], sa[jb]);
        }
      }

      // ---- scale + causal mask + online softmax ----
      float tmax = -1e30f;
      bool diag = (j == t);
#pragma unroll
      for (int jb = 0; jb < 4; ++jb) {
#pragma unroll
        for (int r = 0; r < 4; ++r) {
          float v = sa[jb][r] * scale;
          if (diag && (jb * 16 + lk * 4 + r) > (wid * 16 + lr)) v = -1e30f;
          sa[jb][r] = v;
          tmax = fmaxf(tmax, v);
        }
      }
      tmax = fmaxf(tmax, __shfl_xor(tmax, 16));
      tmax = fmaxf(tmax, __shfl_xor(tmax, 32));
      float m_new = fmaxf(m_run, tmax);
      float alpha = __expf(m_run - m_new);
      float psum = 0.f;
#pragma unroll
      for (int jb = 0; jb < 4; ++jb) {
        float p0 = __expf(sa[jb][0] - m_new);
        float p1 = __expf(sa[jb][1] - m_new);
        float p2 = __expf(sa[jb][2] - m_new);
        float p3 = __expf(sa[jb][3] - m_new);
        psum += (p0 + p1) + (p2 + p3);
        uint2 w;
        w.x = (unsigned int)f2bf(p0) | ((unsigned int)f2bf(p1) << 16);
        w.y = (unsigned int)f2bf(p2) | ((unsigned int)f2bf(p3) << 16);
        *(uint2*)&pl[lr * 80 + jb * 16 + lk * 4] = w;  // P^T via per-wave LDS
      }
      psum += __shfl_xor(psum, 16);
      psum += __shfl_xor(psum, 32);
      l_run = l_run * alpha + psum;
      m_run = m_new;
      float al[4];
#pragma unroll
      for (int r = 0; r < 4; ++r) al[r] = __shfl(alpha, lk * 4 + r);
#pragma unroll
      for (int d = 0; d < 16; ++d) {
#pragma unroll
        for (int r = 0; r < 4; ++r) Oa[d][r] *= al[r];
      }

      // ---- PV: A = P (LDS), B = V fragments from Vt (contiguous 16B, L2) ----
      s16x8 pf0 = *(const s16x8*)&pl[lr * 80 + lk * 8];
      s16x8 pf1 = *(const s16x8*)&pl[lr * 80 + 32 + lk * 8];
#pragma unroll
      for (int d = 0; d < 16; ++d) {
        s16x8 vf0 = *(const s16x8*)&Vt[(size_t)(d * 16 + lr) * T_DIM + kv + lk * 8];
        Oa[d] = mfma16(pf0, vf0, Oa[d]);
      }
#pragma unroll
      for (int d = 0; d < 16; ++d) {
        s16x8 vf1 = *(const s16x8*)&Vt[(size_t)(d * 16 + lr) * T_DIM + kv + 32 + lk * 8];
        Oa[d] = mfma16(pf1, vf1, Oa[d]);
      }
    }
  }

  // store partials (unnormalized O, running m and l)
  float* Op = Opart + ((size_t)s * T_DIM + q0) * D_DIM;
#pragma unroll
  for (int d = 0; d < 16; ++d) {
#pragma unroll
    for (int r = 0; r < 4; ++r)
      Op[(size_t)(lk * 4 + r) * D_DIM + d * 16 + lr] = Oa[d][r];
  }
  if (lane < 16) {
    mpart[(size_t)s * T_DIM + q0 + lr] = m_run;
    lpart[(size_t)s * T_DIM + q0 + lr] = l_run;
  }
}

// ---------------- merge split-KV partials -> final output ---------------------
__global__ __launch_bounds__(256) void merge_kernel(const float* __restrict__ Opart,
                                                    const float* __restrict__ mpart,
                                                    const float* __restrict__ lpart,
                                                    float* __restrict__ out) {
  int q = blockIdx.x;
  int d = threadIdx.x;
  float ms[SPLIT], ls[SPLIT];
  float M = -1e30f;
#pragma unroll
  for (int s = 0; s < SPLIT; ++s) {
    ms[s] = mpart[(size_t)s * T_DIM + q];
    ls[s] = lpart[(size_t)s * T_DIM + q];
    M = fmaxf(M, ms[s]);
  }
  float denom = 0.f, acc = 0.f;
#pragma unroll
  for (int s = 0; s < SPLIT; ++s) {
    float w = __expf(ms[s] - M);
    denom += w * ls[s];
    acc += w * Opart[((size_t)s * T_DIM + q) * D_DIM + d];
  }
  out[(size_t)q * D_DIM + d] = acc / denom;
}

// ---------------- host launch --------------------------------------------------
extern "C" void kernel_launch(void* const* d_in, const int* in_sizes, int n_in,
                              void* d_out, int out_size, void* d_ws, size_t ws_size,
                              hipStream_t stream) {
  const float* x  = (const float*)d_in[0];
  const float* Wq = (const float*)d_in[1];
  const float* Wk = (const float*)d_in[2];
  const float* Wv = (const float*)d_in[3];

  char* ws = (char*)d_ws;
  unsigned short* xb = (unsigned short*)(ws);
  unsigned short* wb = (unsigned short*)(ws + 16777216);
  unsigned short* Qg = (unsigned short*)(ws + 19922944);
  unsigned short* Kg = (unsigned short*)(ws + 22020096);
  unsigned short* Vt = (unsigned short*)(ws + 24117248);
  float* Opart = (float*)(ws + 26214400);
  float* mpart = (float*)(ws + 59768832);
  float* lpart = (float*)(ws + 59899904);

  cvt_kernel<<<4096, 256, 0, stream>>>(x, xb, T_DIM * E_DIM);
  cvt_kernel<<<256, 256, 0, stream>>>(Wq, wb, D_DIM * E_DIM);
  cvt_kernel<<<256, 256, 0, stream>>>(Wk, wb + (size_t)D_DIM * E_DIM, D_DIM * E_DIM);
  cvt_kernel<<<256, 256, 0, stream>>>(Wv, wb + (size_t)2 * D_DIM * E_DIM, D_DIM * E_DIM);

  qkv_gemm<<<32 * 12, 256, 0, stream>>>(xb, wb, Qg, Kg, Vt);

  attn_kernel<<<64 * SPLIT, 256, 0, stream>>>(Qg, Kg, Vt, Opart, mpart, lpart);

  merge_kernel<<<T_DIM, 256, 0, stream>>>(Opart, mpart, lpart, (float*)d_out);
}

// Round 3
// 108.360 us; speedup vs baseline: 1.4607x; 1.1204x over previous
//
#include <hip/hip_runtime.h>
#include <hip/hip_bf16.h>

#define T_DIM 4096
#define E_DIM 2048
#define D_DIM 256

typedef __attribute__((ext_vector_type(4))) float f32x4;
typedef __attribute__((ext_vector_type(8))) short s16x8;

__device__ __forceinline__ unsigned short f2bf(float f) {
  unsigned int u = __float_as_uint(f);
  unsigned int r = (u + 0x7FFFu + ((u >> 16) & 1u)) >> 16;  // RNE
  return (unsigned short)r;
}
__device__ __forceinline__ float bf2f(unsigned short h) {
  return __uint_as_float(((unsigned int)h) << 16);
}

__device__ __forceinline__ f32x4 mfma16(s16x8 a, s16x8 b, f32x4 c) {
  return __builtin_amdgcn_mfma_f32_16x16x32_bf16(a, b, c, 0, 0, 0);
}

__device__ __forceinline__ void gload_lds16(const void* g, void* l) {
  __builtin_amdgcn_global_load_lds((const __attribute__((address_space(1))) void*)g,
                                   (__attribute__((address_space(3))) void*)l, 16, 0, 0);
}

// fbase(t) = sum_{k=1}^{t} ceil(k/3)  (block-index base for q-tile t)
__device__ __forceinline__ int fbase(int t) {
  int g = t / 3, r = t - 3 * g;
  return 3 * g * (g + 1) / 2 + r * (g + 1);
}

// ---------------- fp32 -> bf16 convert (8 elems/thread) -----------------------
__global__ __launch_bounds__(256) void cvt_kernel(const float* __restrict__ src,
                                                  unsigned short* __restrict__ dst, int n) {
  int i = blockIdx.x * blockDim.x + threadIdx.x;
  if (i * 8 + 8 <= n) {
    float4 a = ((const float4*)src)[i * 2];
    float4 b = ((const float4*)src)[i * 2 + 1];
    uint4 o;
    o.x = (unsigned int)f2bf(a.x) | ((unsigned int)f2bf(a.y) << 16);
    o.y = (unsigned int)f2bf(a.z) | ((unsigned int)f2bf(a.w) << 16);
    o.z = (unsigned int)f2bf(b.x) | ((unsigned int)f2bf(b.y) << 16);
    o.w = (unsigned int)f2bf(b.z) | ((unsigned int)f2bf(b.w) << 16);
    ((uint4*)dst)[i] = o;
  }
}

// ---------------- fused QKV projection GEMM -----------------------------------
// C[4096,768] = xb @ wb^T. BM=128, BN=64, BK=64, dbuf DMA, swizzled LDS.
// grid = 384 (XCD-locality remapped). cols: 0-255 Q, 256-511 K, 512-767 V^T.
__global__ __launch_bounds__(256, 3) void qkv_gemm(
    const unsigned short* __restrict__ xb, const unsigned short* __restrict__ wb,
    unsigned short* __restrict__ Qg, unsigned short* __restrict__ Kg,
    unsigned short* __restrict__ Vt) {
  __shared__ __align__(16) unsigned short Al[2][128 * 64];
  __shared__ __align__(16) unsigned short Bl[2][64 * 64];
  int tid = threadIdx.x, wid = tid >> 6, lane = tid & 63;
  int lr = lane & 15, lk = lane >> 4;
  // XCD-locality remap: same XCD sweeps n for a fixed m-panel
  int bi_ = (int)blockIdx.x;
  int xcd = bi_ & 7, kk = bi_ >> 3;
  int mb_ = (kk / 12) * 8 + xcd, nb_ = kk % 12;
  int bm0 = mb_ * 128, bn0 = nb_ * 64;
  int wm = (wid >> 1) * 64, wn = (wid & 1) * 32;

  f32x4 acc[4][2];
#pragma unroll
  for (int m = 0; m < 4; ++m)
#pragma unroll
    for (int n = 0; n < 2; ++n) acc[m][n] = (f32x4){0.f, 0.f, 0.f, 0.f};

#define STAGE_QKV(kt, buf)                                                              \
  {                                                                                     \
    int k0 = (kt)*64;                                                                   \
    _Pragma("unroll") for (int i2 = 0; i2 < 4; ++i2) {                                  \
      int ci = (wid * 4 + i2) * 64 + lane;                                              \
      int row = ci >> 3, cc = ci & 7;                                                   \
      gload_lds16(&xb[(size_t)(bm0 + row) * E_DIM + k0 + ((cc ^ (row & 7)) << 3)],      \
                  &Al[buf][(size_t)(wid * 4 + i2) * 512]);                              \
    }                                                                                   \
    _Pragma("unroll") for (int i2 = 0; i2 < 2; ++i2) {                                  \
      int ci = (wid * 2 + i2) * 64 + lane;                                              \
      int row = ci >> 3, cc = ci & 7;                                                   \
      gload_lds16(&wb[(size_t)(bn0 + row) * E_DIM + k0 + ((cc ^ (row & 7)) << 3)],      \
                  &Bl[buf][(size_t)(wid * 2 + i2) * 512]);                              \
    }                                                                                   \
  }

  STAGE_QKV(0, 0);
  for (int kt = 0; kt < 32; ++kt) {
    int cur = kt & 1;
    __syncthreads();  // drains this wave's DMA (vmcnt 0) + block sync
    if (kt + 1 < 32) STAGE_QKV(kt + 1, cur ^ 1);
    s16x8 af[2][4], bfr[2][2];
#pragma unroll
    for (int c = 0; c < 2; ++c) {
#pragma unroll
      for (int m = 0; m < 4; ++m)
        af[c][m] = *(const s16x8*)&Al[cur][(size_t)(wm + m * 16 + lr) * 64 +
                                           (((c * 4 + lk) ^ (lr & 7)) << 3)];
#pragma unroll
      for (int n = 0; n < 2; ++n)
        bfr[c][n] = *(const s16x8*)&Bl[cur][(size_t)(wn + n * 16 + lr) * 64 +
                                            (((c * 4 + lk) ^ (lr & 7)) << 3)];
    }
#pragma unroll
    for (int c = 0; c < 2; ++c)
#pragma unroll
      for (int m = 0; m < 4; ++m)
#pragma unroll
        for (int n = 0; n < 2; ++n) acc[m][n] = mfma16(af[c][m], bfr[c][n], acc[m][n]);
  }

  // epilogue: C layout col=lane&15, row=(lane>>4)*4+reg
#pragma unroll
  for (int m = 0; m < 4; ++m) {
    int grow = bm0 + wm + m * 16 + lk * 4;
#pragma unroll
    for (int n = 0; n < 2; ++n) {
      int gcol = bn0 + wn + n * 16 + lr;
      unsigned short h[4];
#pragma unroll
      for (int r = 0; r < 4; ++r) h[r] = f2bf(acc[m][n][r]);
      if (gcol < 256) {
#pragma unroll
        for (int r = 0; r < 4; ++r) Qg[(size_t)(grow + r) * D_DIM + gcol] = h[r];
      } else if (gcol < 512) {
#pragma unroll
        for (int r = 0; r < 4; ++r) Kg[(size_t)(grow + r) * D_DIM + gcol - 256] = h[r];
      } else {
        uint2 w;
        w.x = (unsigned int)h[0] | ((unsigned int)h[1] << 16);
        w.y = (unsigned int)h[2] | ((unsigned int)h[3] << 16);
        *(uint2*)&Vt[(size_t)(gcol - 512) * T_DIM + grow] = w;
      }
    }
  }
#undef STAGE_QKV
}

// ---------------- flash attention (causal), balanced variable splits ----------
// 715 blocks; block b -> (t, s): q-tile t (64 rows), kv32-tiles j = 6s..6s+nt-1.
// K and V both staged via async DMA, double-buffered, XOR-swizzled.
__global__ __launch_bounds__(256, 2) void attn_kernel(
    const unsigned short* __restrict__ Qg, const unsigned short* __restrict__ Kg,
    const unsigned short* __restrict__ Vt, unsigned short* __restrict__ Opart,
    float* __restrict__ mpart, float* __restrict__ lpart) {
  __shared__ __align__(16) unsigned short Kl[2][32 * 256];  // 2 x 16KB (swizzled)
  __shared__ __align__(16) unsigned short Vl[2][256 * 32];  // 2 x 16KB (swizzled)
  __shared__ __align__(16) unsigned short Pl[4][16 * 40];   // per-wave P^T

  int b = blockIdx.x;
  int t = (int)sqrtf(6.0f * (float)b + 2.25f);
  if (t > 63) t = 63;
  while (t > 0 && fbase(t) > b) --t;
  while (t < 63 && fbase(t + 1) <= b) ++t;
  int s = b - fbase(t);
  int nt = 2 * t + 2 - 6 * s;
  if (nt > 6) nt = 6;

  int tid = threadIdx.x, wid = tid >> 6, lane = tid & 63;
  int lr = lane & 15, lk = lane >> 4;
  int q0 = t * 64 + wid * 16;
  unsigned short* pl = &Pl[wid][0];

  s16x8 qf[8];
#pragma unroll
  for (int c = 0; c < 8; ++c)
    qf[c] = *(const s16x8*)&Qg[(size_t)(q0 + lr) * D_DIM + c * 32 + lk * 8];

  float m_run = -1e30f, l_run = 0.0f;
  f32x4 Oa[16];
#pragma unroll
  for (int d = 0; d < 16; ++d) Oa[d] = (f32x4){0.f, 0.f, 0.f, 0.f};
  const float scale = 0.0625f;  // 1/sqrt(256)

#define STAGE_KV(j, buf)                                                             \
  {                                                                                  \
    int kv_ = (j)*32;                                                                \
    _Pragma("unroll") for (int i2 = 0; i2 < 4; ++i2) {                               \
      int ci = (wid * 4 + i2) * 64 + lane;                                           \
      int row = ci >> 5, cc = ci & 31;                                               \
      gload_lds16(&Kg[(size_t)(kv_ + row) * D_DIM + ((cc ^ (row & 7)) << 3)],        \
                  &Kl[buf][(size_t)(wid * 4 + i2) * 512]);                           \
    }                                                                                \
    _Pragma("unroll") for (int i2 = 0; i2 < 4; ++i2) {                               \
      int ci = (wid * 4 + i2) * 64 + lane;                                           \
      int rr = ci >> 2, cc = ci & 3;                                                 \
      gload_lds16(&Vt[(size_t)rr * T_DIM + kv_ + ((cc ^ ((rr >> 1) & 3)) << 3)],     \
                  &Vl[buf][(size_t)(wid * 4 + i2) * 512]);                           \
    }                                                                                \
  }

  STAGE_KV(6 * s, 0);
  for (int n = 0; n < nt; ++n) {
    int j = 6 * s + n;
    int kv = j * 32;
    int cur = n & 1;
    __syncthreads();  // drain DMA for buf[cur] + block sync
    if (n + 1 < nt) STAGE_KV(j + 1, cur ^ 1);
    const unsigned short* kl = &Kl[cur][0];
    const unsigned short* vl = &Vl[cur][0];

    // ---- QK^T (swapped: S^T = mfma(K, Q)), lane: q=lr, key=jb*16+lk*4+r ----
    f32x4 sa[2];
    sa[0] = (f32x4){0.f, 0.f, 0.f, 0.f};
    sa[1] = (f32x4){0.f, 0.f, 0.f, 0.f};
#pragma unroll
    for (int jb = 0; jb < 2; ++jb) {
      int row = jb * 16 + lr;
#pragma unroll
      for (int c = 0; c < 8; ++c) {
        s16x8 kf = *(const s16x8*)&kl[(size_t)row * 256 + (((c * 4 + lk) ^ (lr & 7)) << 3)];
        sa[jb] = mfma16(kf, qf[c], sa[jb]);
      }
    }

    // ---- scale + causal mask + online softmax ----
    float tmax = -1e30f;
#pragma unroll
    for (int jb = 0; jb < 2; ++jb) {
#pragma unroll
      for (int r = 0; r < 4; ++r) {
        float v = sa[jb][r] * scale;
        int keyg = kv + jb * 16 + lk * 4 + r;
        if (keyg > q0 + lr) v = -1e30f;
        sa[jb][r] = v;
        tmax = fmaxf(tmax, v);
      }
    }
    tmax = fmaxf(tmax, __shfl_xor(tmax, 16));
    tmax = fmaxf(tmax, __shfl_xor(tmax, 32));
    float m_new = fmaxf(fmaxf(m_run, tmax), -1e29f);  // clamp: all-masked tile safe
    float alpha = __expf(m_run - m_new);
    float psum = 0.f;
#pragma unroll
    for (int jb = 0; jb < 2; ++jb) {
      float p0 = __expf(sa[jb][0] - m_new);
      float p1 = __expf(sa[jb][1] - m_new);
      float p2 = __expf(sa[jb][2] - m_new);
      float p3 = __expf(sa[jb][3] - m_new);
      psum += (p0 + p1) + (p2 + p3);
      uint2 w;
      w.x = (unsigned int)f2bf(p0) | ((unsigned int)f2bf(p1) << 16);
      w.y = (unsigned int)f2bf(p2) | ((unsigned int)f2bf(p3) << 16);
      *(uint2*)&pl[lr * 40 + jb * 16 + lk * 4] = w;  // P^T via per-wave LDS
    }
    psum += __shfl_xor(psum, 16);
    psum += __shfl_xor(psum, 32);
    l_run = l_run * alpha + psum;
    m_run = m_new;
    float al[4];
#pragma unroll
    for (int r = 0; r < 4; ++r) al[r] = __shfl(alpha, lk * 4 + r);
#pragma unroll
    for (int d = 0; d < 16; ++d) {
#pragma unroll
      for (int r = 0; r < 4; ++r) Oa[d][r] *= al[r];
    }

    // ---- PV: A = P (LDS), B = V from swizzled LDS ----
    s16x8 pf = *(const s16x8*)&pl[lr * 40 + lk * 8];
    int vsw = (lk ^ ((lr >> 1) & 3)) << 3;
#pragma unroll
    for (int d = 0; d < 16; ++d) {
      s16x8 vf = *(const s16x8*)&vl[(size_t)(d * 16 + lr) * 32 + vsw];
      Oa[d] = mfma16(pf, vf, Oa[d]);
    }
  }

  // ---- store partials: Opart[b][256 d][64 q] bf16, packed uint2 ----
#pragma unroll
  for (int d = 0; d < 16; ++d) {
    unsigned short h[4];
#pragma unroll
    for (int r = 0; r < 4; ++r) h[r] = f2bf(Oa[d][r]);
    uint2 w;
    w.x = (unsigned int)h[0] | ((unsigned int)h[1] << 16);
    w.y = (unsigned int)h[2] | ((unsigned int)h[3] << 16);
    *(uint2*)&Opart[((size_t)b * 256 + d * 16 + lr) * 64 + wid * 16 + lk * 4] = w;
  }
  if (lane < 16) {
    mpart[(size_t)b * 64 + wid * 16 + lr] = m_run;
    lpart[(size_t)b * 64 + wid * 16 + lr] = l_run;
  }
#undef STAGE_KV
}

// ---------------- merge variable-split partials -> final output ---------------
// grid = 64 q-tiles x 4 d-groups; block: 64 q x 64 d chunk.
__global__ __launch_bounds__(256) void merge_kernel(const unsigned short* __restrict__ Opart,
                                                    const float* __restrict__ mpart,
                                                    const float* __restrict__ lpart,
                                                    float* __restrict__ out) {
  __shared__ float trans[64 * 65];
  int blk = blockIdx.x;
  int t = blk >> 2;
  int d0 = (blk & 3) * 64;
  int q0 = t * 64;
  int ql = threadIdx.x & 63;
  int dg = threadIdx.x >> 6;
  int g = t / 3, r3 = t - 3 * g;
  int base = 3 * g * (g + 1) / 2 + r3 * (g + 1);  // fbase(t)
  int nb = (t + 3) / 3;                           // ceil((t+1)/3)

  // pass 1: global max M and denominator
  float M = -1e30f, den = 0.f;
  for (int p = 0; p < nb; ++p) {
    float mp = mpart[(size_t)(base + p) * 64 + ql];
    float lp = lpart[(size_t)(base + p) * 64 + ql];
    float Mn = fmaxf(M, mp);
    float sc = __expf(M - Mn);
    den = den * sc + __expf(mp - Mn) * lp;
    M = Mn;
  }
  float inv = 1.0f / den;

  // pass 2: weighted O accumulation (static-indexed acc)
  float acc[16];
#pragma unroll
  for (int k = 0; k < 16; ++k) acc[k] = 0.f;
  for (int p = 0; p < nb; ++p) {
    float w = __expf(mpart[(size_t)(base + p) * 64 + ql] - M);
    const unsigned short* oprow = &Opart[((size_t)(base + p) * 256 + d0 + dg) * 64 + ql];
#pragma unroll
    for (int k = 0; k < 16; ++k) acc[k] += w * bf2f(oprow[(size_t)(4 * k) * 64]);
  }
#pragma unroll
  for (int k = 0; k < 16; ++k) trans[(dg + 4 * k) * 65 + ql] = acc[k] * inv;
  __syncthreads();

  // coalesced output writes
#pragma unroll
  for (int k = 0; k < 16; ++k) {
    int qq = (threadIdx.x >> 6) + 4 * k;
    int dd = threadIdx.x & 63;
    out[(size_t)(q0 + qq) * 256 + d0 + dd] = trans[dd * 65 + qq];
  }
}

// ---------------- host launch --------------------------------------------------
extern "C" void kernel_launch(void* const* d_in, const int* in_sizes, int n_in,
                              void* d_out, int out_size, void* d_ws, size_t ws_size,
                              hipStream_t stream) {
  const float* x  = (const float*)d_in[0];
  const float* Wq = (const float*)d_in[1];
  const float* Wk = (const float*)d_in[2];
  const float* Wv = (const float*)d_in[3];

  char* ws = (char*)d_ws;
  // workspace layout (bytes):
  //   xb    [4096][2048] bf16 : 16,777,216   @ 0
  //   wb    [768][2048]  bf16 :  3,145,728   @ 16,777,216
  //   Qg    [4096][256]  bf16 :  2,097,152   @ 19,922,944
  //   Kg    [4096][256]  bf16 :  2,097,152   @ 22,020,096
  //   Vt    [256][4096]  bf16 :  2,097,152   @ 24,117,248
  //   Opart [715][256][64] bf16: 23,429,120  @ 26,214,400
  //   mpart [715][64] f32     :    183,040   @ 49,643,520
  //   lpart [715][64] f32     :    183,040   @ 49,826,560   (total ~50.0 MB)
  unsigned short* xb = (unsigned short*)(ws);
  unsigned short* wb = (unsigned short*)(ws + 16777216);
  unsigned short* Qg = (unsigned short*)(ws + 19922944);
  unsigned short* Kg = (unsigned short*)(ws + 22020096);
  unsigned short* Vt = (unsigned short*)(ws + 24117248);
  unsigned short* Opart = (unsigned short*)(ws + 26214400);
  float* mpart = (float*)(ws + 49643520);
  float* lpart = (float*)(ws + 49826560);

  cvt_kernel<<<4096, 256, 0, stream>>>(x, xb, T_DIM * E_DIM);
  cvt_kernel<<<256, 256, 0, stream>>>(Wq, wb, D_DIM * E_DIM);
  cvt_kernel<<<256, 256, 0, stream>>>(Wk, wb + (size_t)D_DIM * E_DIM, D_DIM * E_DIM);
  cvt_kernel<<<256, 256, 0, stream>>>(Wv, wb + (size_t)2 * D_DIM * E_DIM, D_DIM * E_DIM);

  qkv_gemm<<<384, 256, 0, stream>>>(xb, wb, Qg, Kg, Vt);

  attn_kernel<<<715, 256, 0, stream>>>(Qg, Kg, Vt, Opart, mpart, lpart);

  merge_kernel<<<256, 256, 0, stream>>>(Opart, mpart, lpart, (float*)d_out);
}